// Round 4
// baseline (437.556 us; speedup 1.0000x reference)
//
#include <hip/hip_runtime.h>

// ---------------------------------------------------------------------------
// LayerStacks (NNUE-style) on MI355X.
//   h0 = clamp01( x @ (w0[b]+w_fact)^T + b0[b] )   // 1024 -> 32, bf16 MFMA
//   h1 = clamp01( h0 @ w1[b]^T + b1[b] )           // 32 -> 32,  fp32 VALU
//   out = h1 @ w2[b]^T + b2[b]                     // 32 -> 1,   fp32 VALU
// R4: no sort, all 8 buckets/row. R5 (FAIL): direct-global A = 32-line-split
// loads. R6: K-chunked dbuf pipeline, ~145us inferred. R7: LOCAL bucket sort
// per 64-row block: rows staged coalesced as before, but row INDICES are
// sorted by bucket in LDS (atomics); MFMA runs only the ~8-9 present-bucket
// tiles (ragged, masked) instead of 16 all-bucket tiles. A-frag "gather" is a
// free per-lane LDS row offset. 2x less MFMA + 2x less L2 weight traffic per
// row; grid=1024, ~18.5KB LDS -> 4 blocks/CU all resident from t=0.
// ---------------------------------------------------------------------------

#define B_ROWS 65536
#define LK     1024       // 2*L1
#define ROWS   64         // rows per block
#define NBLK   (B_ROWS / ROWS)   // 1024, exact
#define KC     64         // K-chunk (bf16 elems)
#define NCH    (LK / KC)  // 16
#define SROW   136        // LDS bytes per row per chunk (128 data + 8 pad)
#define BUFSZ  (ROWS * SROW)     // 8704
#define MAXNT  9          // max tiles: sum ceil(n_b/32), sum n_b=64 -> <= 9

// ws layout (bytes):
//   [0, 524288)       : wB bf16 B-frags of (w0+w_fact): per bucket 4096 uint4;
//                       frag c*64+l = W[bkt*32 + (l&31)][16c + 8*(l>>5) .. +8]
//   [524288, 589824)  : bktg[65536] uchar per-row bucket
#define BKT_OFF 524288

typedef short  short8  __attribute__((ext_vector_type(8)));
typedef float  f32x16  __attribute__((ext_vector_type(16)));

__device__ __forceinline__ unsigned pkbf(float a, float b) {
    // round-to-nearest-even fp32 -> bf16, packed pair (bit-trick)
    unsigned ua = __float_as_uint(a), ub = __float_as_uint(b);
    ua = (ua + 0x7FFFu + ((ua >> 16) & 1u)) >> 16;
    ub = (ub + 0x7FFFu + ((ub >> 16) & 1u)) >> 16;
    return (ua & 0xFFFFu) | (ub << 16);
}

__device__ __forceinline__ unsigned cvtpk(float a, float b) {
    // RTNE fp32->bf16 packed pair, single instruction on gfx950
    unsigned r;
    asm("v_cvt_pk_bf16_f32 %0, %1, %2" : "=v"(r) : "v"(a), "v"(b));
    return r;
}

// ls_indices may be int32 or int64. If int64, the high words (odd int32
// slots) of the first 64 elements are all zero (values 0..7). Deterministic.
__device__ __forceinline__ bool detect_i64(const int* p) {
    int acc = 0;
#pragma unroll
    for (int i = 0; i < 64; ++i) acc |= p[2 * i + 1];
    return acc == 0;
}

__device__ __forceinline__ int load_bucket(const int* p, int r, bool i64) {
    return (i64 ? p[2 * r] : p[r]) & 7;
}

// --- K1: weight prep + bucket decode ----------------------------------------
// Blocks 0..31: build bf16 B-fragments of (w0+w_fact), 1 frag/thread.
// Block 32: decode ls_indices -> bktg[65536] uchar.
__global__ __launch_bounds__(1024) void k_prep(
    const int* __restrict__ idx, const float* __restrict__ w0,
    const float* __restrict__ wf, uint4* __restrict__ wB,
    unsigned char* __restrict__ bktg)
{
    int t = threadIdx.x;
    if (blockIdx.x == 32) {
        __shared__ int s_i64;
        if (t == 0) s_i64 = detect_i64(idx) ? 1 : 0;
        __syncthreads();
        bool i64 = (s_i64 != 0);
#pragma unroll 4
        for (int j = 0; j < 64; ++j)
            bktg[j * 1024 + t] = (unsigned char)load_bucket(idx, j * 1024 + t, i64);
        return;
    }
    int f = blockIdx.x * 1024 + t;             // 32768 frags
    int b   = f >> 12;
    int i12 = f & 4095;
    int kc  = i12 >> 8;
    int i8  = i12 & 255;
    int n   = i8 & 31;
    int khi = i8 >> 5;
    int k = kc * 64 + khi * 8;                 // == c*16 + 8*(lane>>5)
    const float* p0 = w0 + (size_t)(b * 32 + n) * LK + k;
    const float* pf = wf + (size_t)n * LK + k;
    float v[8];
#pragma unroll
    for (int j = 0; j < 8; ++j) v[j] = p0[j] + pf[j];
    uint4 o;
    o.x = pkbf(v[0], v[1]); o.y = pkbf(v[2], v[3]);
    o.z = pkbf(v[4], v[5]); o.w = pkbf(v[6], v[7]);
    wB[f] = o;
}

// --- K2: main fused kernel ---------------------------------------------------
// Block = 256 thr = 4 waves; 64 consecutive rows. Rows locally sorted by
// bucket (indices only, in LDS). Tiles (bucket, start, len<=32) assigned
// round-robin to waves (slot s: tile wv+4s, <=3 slots). K double-buffered in
// chunks of 64 elems; per chunk each wave does <=3 tiles x 4 MFMAs with
// per-lane scattered LDS row reads. Epilogue scatters h0 by original row,
// then layers 1+2 fp32 with 4 threads/row.
__global__ __launch_bounds__(256, 4) void k_main(
    const float* __restrict__ x, const unsigned char* __restrict__ bktg,
    const uint4* __restrict__ wB, const float* __restrict__ b0,
    const float* __restrict__ w1, const float* __restrict__ b1,
    const float* __restrict__ w2, const float* __restrict__ b2,
    float* __restrict__ out)
{
    __shared__ __align__(16) unsigned char a_s[2 * BUFSZ];   // 17408 B
    __shared__ int bkt_s[ROWS];
    __shared__ unsigned short order[ROWS];
    __shared__ int cnt8[8], cur8[8];
    __shared__ int tb_b[MAXNT], tb_s0[MAXNT], tb_l[MAXNT];
    __shared__ int NT_s;

    float* hb = (float*)a_s;    // h0 [64][36], aliases a_s AFTER final barrier

    int row0 = blockIdx.x * ROWS;
    int t    = threadIdx.x;
    int lane = t & 63;
    int wv   = t >> 6;
    int hi   = lane >> 5;
    int nn   = lane & 31;

    // ---- issue chunk-0 x loads early (latency hides under the local sort)
    // float4 f = 256q + t of chunk: row = 16q + (t>>4), col4 = t&15.
    const float4* gp = (const float4*)x + (size_t)(row0 + (t >> 4)) * 256 + (t & 15);
    float4 v[4];
#pragma unroll
    for (int q = 0; q < 4; ++q) v[q] = gp[q * 4096];

    // ---- local bucket sort of 64 row indices
    if (t < 8) cnt8[t] = 0;
    __syncthreads();
    int myb = 0;
    if (t < ROWS) {
        myb = (int)bktg[row0 + t];
        bkt_s[t] = myb;
        atomicAdd(&cnt8[myb], 1);
    }
    __syncthreads();
    if (t == 0) {
        int base = 0, nt = 0;
        for (int b = 0; b < 8; ++b) {
            int n = cnt8[b];
            cur8[b] = base;
            for (int j = 0; j < n; j += 32) {
                tb_b[nt] = b; tb_s0[nt] = base + j; tb_l[nt] = min(32, n - j);
                nt++;
            }
            base += n;
        }
        NT_s = nt;
    }
    __syncthreads();
    if (t < ROWS) {
        int pos = atomicAdd(&cur8[myb], 1);
        order[pos] = (unsigned short)t;
    }

    // ---- pack + write chunk 0 (vmcnt wait here; sort hid part of latency)
    const int wb_off = (t >> 4) * SROW + (t & 15) * 8;
#pragma unroll
    for (int q = 0; q < 4; ++q) {
        uint2 o; o.x = cvtpk(v[q].x, v[q].y); o.y = cvtpk(v[q].z, v[q].w);
        *(uint2*)(a_s + wb_off + q * 16 * SROW) = o;
    }
    __syncthreads();

    // ---- per-slot setup: tile tau = wv + 4s
    int NT = NT_s;
    int vs[3], sl[3], ss[3], aoff[3];
    const uint4* wp[3];
    float b0v[3];
    f32x16 acc[3];
#pragma unroll
    for (int s = 0; s < 3; ++s) {
        int tau = wv + 4 * s;
        int val = (tau < NT) ? 1 : 0;
        int b  = val ? tb_b[tau]  : 0;
        int st = val ? tb_s0[tau] : 0;
        int ln = val ? tb_l[tau]  : 0;
        int rr = (nn < ln) ? (int)order[st + nn] : 0;   // guarded: in-bounds
        vs[s] = val; sl[s] = ln; ss[s] = st;
        aoff[s] = rr * SROW + 16 * hi;
        wp[s]   = wB + (size_t)b * 4096 + lane;
        b0v[s]  = b0[b * 32 + nn];
#pragma unroll
        for (int i = 0; i < 16; ++i) acc[s][i] = 0.0f;
    }

    // ---- K-loop: 16 chunks, double-buffered
    union UAB { uint4 u; short8 s8; };
    for (int ck = 0; ck < NCH; ++ck) {
        const unsigned char* cur = a_s + (ck & 1) * BUFSZ;
        unsigned char* nxt = a_s + ((ck + 1) & 1) * BUFSZ;
        if (ck + 1 < NCH) {
#pragma unroll
            for (int q = 0; q < 4; ++q) v[q] = gp[q * 4096 + (ck + 1) * 16];
        }
#pragma unroll
        for (int s = 0; s < 3; ++s) {
            if (vs[s]) {                              // wave-uniform branch
#pragma unroll
                for (int cc = 0; cc < 4; ++cc) {
                    UAB ua, ub;
                    ua.u = *(const uint4*)(cur + aoff[s] + 32 * cc);
                    ub.u = wp[s][(4 * ck + cc) * 64];  // L2-resident
                    acc[s] = __builtin_amdgcn_mfma_f32_32x32x16_bf16(
                                 ua.s8, ub.s8, acc[s], 0, 0, 0);
                }
            }
        }
        if (ck + 1 < NCH) {
#pragma unroll
            for (int q = 0; q < 4; ++q) {
                uint2 o; o.x = cvtpk(v[q].x, v[q].y); o.y = cvtpk(v[q].z, v[q].w);
                *(uint2*)(nxt + wb_off + q * 16 * SROW) = o;
            }
        }
        __syncthreads();   // last iteration's barrier also protects hb alias
    }

    // ---- scatter h0 to hb by ORIGINAL row: C elem (reg i, lane l):
    //      m = (i&3)+8*(i>>2)+4*(l>>5) (row-in-tile), n = l&31
#pragma unroll
    for (int s = 0; s < 3; ++s) {
        if (vs[s]) {
#pragma unroll
            for (int i = 0; i < 16; ++i) {
                int m = (i & 3) + 8 * (i >> 2) + 4 * hi;
                if (m < sl[s]) {
                    int r = (int)order[ss[s] + m];
                    float h = acc[s][i] + b0v[s];
                    hb[r * 36 + nn] = fminf(fmaxf(h, 0.0f), 1.0f);
                }
            }
        }
    }
    __syncthreads();

    // ---- layers 1+2 (fp32): 4 threads per row, 8 outputs each
    {
        int r  = t >> 2;            // 0..63
        int qt = t & 3;
        int bkt = bkt_s[r];
        const float4* hr = (const float4*)(hb + r * 36);
        float4 ha[8];
#pragma unroll
        for (int q = 0; q < 8; ++q) ha[q] = hr[q];
        const float* w1b = w1 + (size_t)bkt * 1024;
        const float* b1b = b1 + bkt * 32;
        const float* w2b = w2 + bkt * 32;
        float partial = 0.0f;
#pragma unroll
        for (int jj = 0; jj < 8; ++jj) {
            int j2 = qt * 8 + jj;
            const float4* wr = (const float4*)&w1b[j2 * 32];
            float s = b1b[j2];
#pragma unroll
            for (int q = 0; q < 8; ++q) {
                float4 w4 = wr[q];
                s += ha[q].x * w4.x + ha[q].y * w4.y + ha[q].z * w4.z + ha[q].w * w4.w;
            }
            s = fminf(fmaxf(s, 0.0f), 1.0f);
            partial += s * w2b[j2];
        }
        partial += __shfl_xor(partial, 1);
        partial += __shfl_xor(partial, 2);
        if (qt == 0) out[row0 + r] = partial + b2[bkt];
    }
}

// ---------------------------------------------------------------------------
extern "C" void kernel_launch(void* const* d_in, const int* in_sizes, int n_in,
                              void* d_out, int out_size, void* d_ws, size_t ws_size,
                              hipStream_t stream) {
    const float* x   = (const float*)d_in[0];
    const int*   lsi = (const int*)  d_in[1];
    const float* wf  = (const float*)d_in[2];
    const float* w0  = (const float*)d_in[3];
    const float* b0  = (const float*)d_in[4];
    const float* w1  = (const float*)d_in[5];
    const float* b1  = (const float*)d_in[6];
    const float* w2  = (const float*)d_in[7];
    const float* b2  = (const float*)d_in[8];
    float* out = (float*)d_out;

    char* ws = (char*)d_ws;
    uint4* wB = (uint4*)ws;
    unsigned char* bktg = (unsigned char*)(ws + BKT_OFF);

    k_prep<<<33, 1024, 0, stream>>>(lsi, w0, wf, wB, bktg);
    k_main<<<NBLK, 256, 0, stream>>>(x, bktg, wB, b0, w1, b1, w2, b2, out);
}